// Round 3
// baseline (2452.837 us; speedup 1.0000x reference)
//
#include <hip/hip_runtime.h>

typedef short b16x8 __attribute__((ext_vector_type(8)));
typedef float f32x4 __attribute__((ext_vector_type(4)));
typedef unsigned short u16;

#define HN 8
#define C  256
#define W  96
#define H  96
#define KW 9
#define K  (C * KW)        // 2304
#define HW (H * W)         // 9216
#define LDS_PITCH 264      // 256 + 8 pad: breaks 512B-stride bank conflict
#define LDS_ROWS  56       // 48 w + 8 halo

__device__ __forceinline__ u16 f2b(float x) {
    union { float f; unsigned int u; } c; c.f = x;
    unsigned int u = c.u;
    unsigned int r = (u + 0x7fffu + ((u >> 16) & 1u)) >> 16;  // RNE
    return (u16)r;
}

// ---------------------------------------------------------------------------
// init: Wr[co][kk*256+ci] = bf16(W[co][ci][kk]); out row0 = fea row0;
//       carry0[n][w][c] = bf16(fea row0)
// ---------------------------------------------------------------------------
__global__ void init_k(const float* __restrict__ fea, const float* __restrict__ Wsrc,
                       u16* __restrict__ Wr, u16* __restrict__ carry0,
                       float* __restrict__ outp)
{
    int t = blockIdx.x * 256 + threadIdx.x;
    if (t < C * K) {
        int co  = t / K;
        int rme = t - co * K;
        int kk  = rme >> 8;      // K = 9*256 exactly
        int ci  = rme & 255;
        Wr[t] = f2b(Wsrc[(co * C + ci) * KW + kk]);
    }
    if (t < HN * C * W) {
        int n   = t / (C * W);
        int rme = t - n * (C * W);
        int c   = rme / W;
        int w   = rme - c * W;
        float v = fea[(size_t)(n * C + c) * HW + w];     // h = 0
        outp[(size_t)(n * C + c) * HW + w] = v;
        carry0[((size_t)n * W + w) * C + c] = f2b(v);
    }
}

// ---------------------------------------------------------------------------
// one recurrence step: out = relu(conv(src) + b) + res  (fp32), dst = bf16(out)
// grid: 256 blocks = 8 n * 16 co-tiles * 2 w-halves; 1 wave per block.
// src carry layout: [n][w][c] bf16. res/outp point at row base (h folded in),
// element offset (n*256+co)*9216 + w.
// ---------------------------------------------------------------------------
__global__ __launch_bounds__(64) void step_k(
    const u16* __restrict__ Wr, const float* __restrict__ bias,
    const u16* __restrict__ src, u16* __restrict__ dst,
    const float* __restrict__ res, float* __restrict__ outp)
{
    __shared__ __align__(16) u16 lds[LDS_ROWS * LDS_PITCH];

    const int bx     = blockIdx.x;
    const int n      = bx >> 5;
    const int cotile = (bx >> 1) & 15;
    const int wh     = bx & 1;
    const int wbase  = wh * 48;
    const int cobase = cotile * 16;
    const int lane   = (int)threadIdx.x;
    const int col    = lane & 15;   // M-row for A, N-col for B, col of D
    const int kg     = lane >> 4;   // k-group (0..3)

    // ---- stage carry row, transposed [w_local][ci], bf16, zero halo ----
    {
        const int ci = (lane & 31) * 8;
        #pragma unroll
        for (int it = 0; it < 28; ++it) {
            int r = it * 2 + (lane >> 5);      // 0..55
            int w = wbase - 4 + r;
            b16x8 v = {0, 0, 0, 0, 0, 0, 0, 0};
            if (w >= 0 && w < W)
                v = *(const b16x8*)(src + ((size_t)(n * W + w) * C + ci));
            *(b16x8*)&lds[r * LDS_PITCH + ci] = v;
        }
    }
    __syncthreads();

    // ---- K-loop: k = kk*256 + ci, stepped 32 at a time (72 iters) ----
    f32x4 acc0 = {0.f, 0.f, 0.f, 0.f};
    f32x4 acc1 = {0.f, 0.f, 0.f, 0.f};
    f32x4 acc2 = {0.f, 0.f, 0.f, 0.f};
    const u16* wp = Wr + (size_t)(cobase + col) * K + kg * 8;
    for (int kk = 0; kk < KW; ++kk) {
        const u16* lrow = &lds[(col + kk) * LDS_PITCH + kg * 8];
        #pragma unroll
        for (int cb = 0; cb < 8; ++cb) {
            b16x8 a = *(const b16x8*)wp; wp += 32;
            const u16* lp = lrow + cb * 32;
            b16x8 b0 = *(const b16x8*)(lp);
            b16x8 b1 = *(const b16x8*)(lp + 16 * LDS_PITCH);
            b16x8 b2 = *(const b16x8*)(lp + 32 * LDS_PITCH);
            acc0 = __builtin_amdgcn_mfma_f32_16x16x32_bf16(a, b0, acc0, 0, 0, 0);
            acc1 = __builtin_amdgcn_mfma_f32_16x16x32_bf16(a, b1, acc1, 0, 0, 0);
            acc2 = __builtin_amdgcn_mfma_f32_16x16x32_bf16(a, b2, acc2, 0, 0, 0);
        }
    }

    // ---- epilogue: D[row=4*kg+r][col], bias+relu+residual, fp32 out + bf16 carry
    #pragma unroll
    for (int nt = 0; nt < 3; ++nt) {
        f32x4 acc = (nt == 0) ? acc0 : ((nt == 1) ? acc1 : acc2);
        int w = wbase + nt * 16 + col;
        #pragma unroll
        for (int r = 0; r < 4; ++r) {
            int co = cobase + kg * 4 + r;
            float y = acc[r] + bias[co];
            y = fmaxf(y, 0.f);
            size_t gidx = (size_t)(n * C + co) * HW + w;
            float o = y + res[gidx];
            outp[gidx] = o;
            dst[((size_t)n * W + w) * C + co] = f2b(o);
        }
    }
}

// ---------------------------------------------------------------------------
extern "C" void kernel_launch(void* const* d_in, const int* in_sizes, int n_in,
                              void* d_out, int out_size, void* d_ws, size_t ws_size,
                              hipStream_t stream)
{
    const float* fea  = (const float*)d_in[0];
    const float* Wsrc = (const float*)d_in[1];
    const float* bias = (const float*)d_in[2];
    float* outp = (float*)d_out;

    u16* Wr = (u16*)d_ws;                       // 589824 bf16
    u16* c0 = Wr + (size_t)C * K;               // carry ping  (8*96*256)
    u16* c1 = c0 + (size_t)HN * W * C;          // carry pong

    init_k<<<dim3((C * K + 255) / 256), dim3(256), 0, stream>>>(fea, Wsrc, Wr, c0, outp);

    u16* src = c0;
    u16* dst = c1;
    // downward: s[i] = relu(conv(s[i-1])+b) + fea[i]
    for (int i = 1; i < H; ++i) {
        step_k<<<dim3(256), dim3(64), 0, stream>>>(Wr, bias, src, dst,
            fea + (size_t)i * W, outp + (size_t)i * W);
        u16* t = src; src = dst; dst = t;
    }
    // upward: s[pos] = relu(conv(s[pos+1])+b) + s_down[pos]   (s_down lives in d_out)
    for (int pos = H - 2; pos >= 0; --pos) {
        step_k<<<dim3(256), dim3(64), 0, stream>>>(Wr, bias, src, dst,
            outp + (size_t)pos * W, outp + (size_t)pos * W);
        u16* t = src; src = dst; dst = t;
    }
}